// Round 13
// baseline (542.963 us; speedup 1.0000x reference)
//
#include <hip/hip_runtime.h>
#include <math.h>

// B=64, N_in=1152, K_in=8, N_out=64, K_out=16, ITER=3
// 32x32x16 MFMA path: rows = 2 o x 16 k, cols = 32 b, K-slots = (xhi,xlo) x 8 j.
// W kept bf16-hi only (error ~3e-4); x split hi/lo for fp32-accurate x.
// Grid 256 = 2 btile x 128 chunk; 1024 thr (16 waves, 4 o/wave via 2 MFMAs).

#define CTI 9         // i per chunk
#define CNCH 128      // 1152 / CTI

typedef __attribute__((ext_vector_type(8))) short short8v;
typedef __attribute__((ext_vector_type(8))) unsigned short ushort8v;
typedef __attribute__((ext_vector_type(4))) float f32x4;
typedef __attribute__((ext_vector_type(16))) float f32x16;

typedef const __attribute__((address_space(1))) unsigned int gu32;
typedef __attribute__((address_space(3))) unsigned int lu32;

__device__ __forceinline__ unsigned short f2bf(float f) {   // RTNE
    unsigned u = __builtin_bit_cast(unsigned, f);
    u = u + 0x7FFFu + ((u >> 16) & 1u);
    return (unsigned short)(u >> 16);
}
__device__ __forceinline__ float bf2f(unsigned short h) {
    unsigned u = ((unsigned)h) << 16;
    return __builtin_bit_cast(float, u);
}
__device__ __forceinline__ float lo16f(unsigned u) {
    return __builtin_bit_cast(float, u << 16);
}
__device__ __forceinline__ float hi16f(unsigned u) {
    return __builtin_bit_cast(float, u & 0xFFFF0000u);
}
__device__ __forceinline__ unsigned packbf(float a, float b) {
    return (unsigned)f2bf(a) | ((unsigned)f2bf(b) << 16);
}

// W[o][i][k][j] f32 -> Wp[i][o][k][j] bf16 (hi only); x -> xp[i][p][b][j] hi/lo
__global__ __launch_bounds__(256)
void xform(const float* __restrict__ W, const float* __restrict__ x,
           unsigned short* __restrict__ Wp, unsigned short* __restrict__ xpp) {
    const int bid = blockIdx.x;
    if (bid < 4608) {
        int tid = bid * 256 + threadIdx.x;          // 1152*64*16
        int k = tid & 15, o = (tid >> 4) & 63, i = tid >> 10;
        const float4* src = (const float4*)(W + (((size_t)o * 1152 + i) * 16 + k) * 8);
        float4 v0 = src[0], v1 = src[1];
        float vf[8] = {v0.x, v0.y, v0.z, v0.w, v1.x, v1.y, v1.z, v1.w};
        ushort8v hi;
        #pragma unroll
        for (int j = 0; j < 8; ++j) hi[j] = f2bf(vf[j]);
        *reinterpret_cast<ushort8v*>(Wp + (((size_t)i * 64 + o) * 16 + k) * 8) = hi;
    } else {
        int tid = (bid - 4608) * 256 + threadIdx.x; // 1152*64
        int b = tid & 63, i = tid >> 6;
        const float4* src = (const float4*)(x + ((size_t)b * 1152 + i) * 8);
        float4 v0 = src[0], v1 = src[1];
        float vf[8] = {v0.x, v0.y, v0.z, v0.w, v1.x, v1.y, v1.z, v1.w};
        ushort8v hi, lo;
        #pragma unroll
        for (int j = 0; j < 8; ++j) {
            unsigned short h = f2bf(vf[j]);
            hi[j] = h;
            lo[j] = f2bf(vf[j] - bf2f(h));
        }
        size_t base = ((size_t)i * 2) * 512 + (size_t)b * 8;
        *reinterpret_cast<ushort8v*>(xpp + base)       = hi;
        *reinterpret_cast<ushort8v*>(xpp + base + 512) = lo;
    }
}

// Routing pass. Grid 256 = bt(2) x chunk(128); bt-sharers differ by 128 -> same XCD.
// 1024 thr = 16 waves; wave wv: o = wv*4..+3 via 2 MFMAs (rows = 2o x 16k).
// Lanes: col b = l&31 (+bt*32), x-plane h = l>>5. Wp slice 16KB/i, dbuf DMA.
template<int ROUTED>
__global__ __launch_bounds__(1024, 1)
void caps32(const unsigned short* __restrict__ Wp,
            const unsigned short* __restrict__ xp,
            const unsigned int* __restrict__ Vfpb,
            unsigned short* __restrict__ spart) {
    __shared__ unsigned short wlds[2][8192];   // 2 x 16 KB, [o][k][j] bf16 hi
    __shared__ float zbuf[2][512];             // [parity][wave][b31]

    const int t = threadIdx.x;
    const int wv = t >> 6, l = t & 63;
    const int bt = blockIdx.x >> 7, chunk = blockIdx.x & 127;
    const int b31 = l & 31, h = l >> 5;
    const int o0 = wv * 4;
    const int i0 = chunk * CTI;

    // A-frag LDS offsets: row r = l&31 -> o += r>>4, k = r&15 (same for both h)
    const int aoff0 = ((o0     + ((l >> 4) & 1)) * 16 + (l & 15)) * 8;
    const int aoff1 = aoff0 + 256;   // +2 o's

    unsigned vpk[16];
    if (ROUTED) {
        const uint4* vsrc = reinterpret_cast<const uint4*>(
            Vfpb + ((size_t)bt * 1024 + t) * 16);
        #pragma unroll
        for (int q = 0; q < 4; ++q) {
            uint4 w = vsrc[q];
            vpk[q*4+0] = w.x; vpk[q*4+1] = w.y; vpk[q*4+2] = w.z; vpk[q*4+3] = w.w;
        }
    }

    f32x16 s0, s1;
    #pragma unroll
    for (int r = 0; r < 16; ++r) { s0[r] = 0.f; s1[r] = 0.f; }

    #define STAGE(buf, i)                                                         \
        __builtin_amdgcn_global_load_lds(                                         \
            (gu32*)(Wp + (size_t)(i) * 8192 + t * 8),                             \
            (lu32*)&wlds[buf][(size_t)wv * 512], 16, 0, 0);

    #define LOADB(i) (*reinterpret_cast<const short8v*>(                          \
        xp + (((size_t)(i) * 2 + h) * 64 + bt * 32 + b31) * 8))

    STAGE(0, i0);
    short8v Bf = LOADB(i0);
    __syncthreads();   // prologue DMA complete

    int cur = 0;
    for (int ii = 0; ii < CTI; ++ii) {
        short8v Bn = Bf;
        if (ii + 1 < CTI) {
            STAGE(cur ^ 1, i0 + ii + 1);
            Bn = LOADB(i0 + ii + 1);
        }

        const unsigned short* wb = &wlds[cur][0];
        short8v A0 = *reinterpret_cast<const short8v*>(wb + aoff0);
        short8v A1 = *reinterpret_cast<const short8v*>(wb + aoff1);

        if (!ROUTED) {
            s0 = __builtin_amdgcn_mfma_f32_32x32x16_bf16(A0, Bf, s0, 0, 0, 0);
            s1 = __builtin_amdgcn_mfma_f32_32x32x16_bf16(A1, Bf, s1, 0, 0, 0);
            __syncthreads();   // DMA(next) drained + buffer reuse
        } else {
            f32x16 zz;
            #pragma unroll
            for (int r = 0; r < 16; ++r) zz[r] = 0.f;
            f32x16 u0 = __builtin_amdgcn_mfma_f32_32x32x16_bf16(A0, Bf, zz, 0, 0, 0);
            f32x16 u1 = __builtin_amdgcn_mfma_f32_32x32x16_bf16(A1, Bf, zz, 0, 0, 0);

            // logits: lane holds 8 k's per oo (other 8 k's live in partner l^32)
            float lg[4], Zp = 0.f;
            #pragma unroll
            for (int oo = 0; oo < 4; ++oo) {
                float p = 0.f;
                #pragma unroll
                for (int j = 0; j < 8; ++j) {
                    int r = oo * 8 + j;                 // flat 0..31
                    float uv = (r < 16) ? ((const float*)&u0)[r] : ((const float*)&u1)[r - 16];
                    unsigned w = vpk[r >> 1];
                    float vv = (r & 1) ? hi16f(w) : lo16f(w);
                    p = fmaf(uv, vv, p);
                }
                p += __shfl_xor(p, 32, 64);             // partner k-half
                float e = __expf(p);                    // |logit| <= ~1.3: safe
                lg[oo] = e;
                Zp += e;
            }
            if (l < 32) zbuf[ii & 1][wv * 32 + l] = Zp;
            __syncthreads();                            // Z visible; DMA drained
            float Z = zbuf[ii & 1][b31];
            #pragma unroll
            for (int w2 = 1; w2 < 16; ++w2) Z += zbuf[ii & 1][w2 * 32 + b31];
            float rz = 1.0f / Z;
            float c0 = lg[0] * rz, c1 = lg[1] * rz, c2 = lg[2] * rz, c3 = lg[3] * rz;
            #pragma unroll
            for (int r = 0; r < 16; ++r) {
                s0[r] = fmaf((r < 8) ? c0 : c1, u0[r], s0[r]);
                s1[r] = fmaf((r < 8) ? c2 : c3, u1[r], s1[r]);
            }
        }
        Bf = Bn;
        cur ^= 1;
    }

    // bf16 partials: [chunk][bt][t][32], 64B/lane coalesced
    const float fin = ROUTED ? 1.0f : (1.0f / 64.0f);
    unsigned pk[16];
    #pragma unroll
    for (int w = 0; w < 8; ++w) {
        pk[w]     = packbf(s0[2*w] * fin, s0[2*w+1] * fin);
        pk[8 + w] = packbf(s1[2*w] * fin, s1[2*w+1] * fin);
    }
    uint4* dst = reinterpret_cast<uint4*>(
        (unsigned int*)spart + (((size_t)chunk * 2 + bt) * 1024 + t) * 16);
    #pragma unroll
    for (int q = 0; q < 4; ++q)
        dst[q] = make_uint4(pk[q*4+0], pk[q*4+1], pk[q*4+2], pk[q*4+3]);
    #undef STAGE
    #undef LOADB
}

// Sum CNCH bf16 partials per fragment cell, squash, update Vsum / write out.
// Grid 256 x 256: wave = one (bt, t/t^32) column pair; lane: w5 = col half, v = value.
template<int MODE>
__global__ __launch_bounds__(256)
void reduce32(const unsigned short* __restrict__ spart, float* __restrict__ Vfp32,
              unsigned int* __restrict__ Vfpb, float* __restrict__ out) {
    const int t = threadIdx.x;
    const int w = t >> 6, l = t & 63;
    const int w5 = l >> 5, v = l & 31;
    const int pg = blockIdx.x * 4 + w;          // 0..1023 column pairs
    const int bt = pg >> 9, p9 = pg & 511;
    const int tc = ((p9 >> 5) << 6) | (w5 << 5) | (p9 & 31);   // caps thread idx

    float acc = 0.f;
    const unsigned short* base = spart + (((size_t)bt * 1024 + tc) * 32) + v;
    #pragma unroll 8
    for (int c = 0; c < CNCH; ++c)
        acc += bf2f(base[(size_t)c * 65536]);

    // n2 over 16 k = butterfly over lane bits {0,1,2,5}
    float sq = acc * acc;
    sq += __shfl_xor(sq, 1, 64);
    sq += __shfl_xor(sq, 2, 64);
    sq += __shfl_xor(sq, 4, 64);
    sq += __shfl_xor(sq, 32, 64);
    const float scale = sq / (1.0f + sq) / sqrtf(sq + 1e-7f);

    const size_t vidx = ((size_t)bt * 1024 + tc) * 32 + v;
    if (MODE == 0) {
        float val = acc * scale;
        Vfp32[vidx] = val;
        float other = __shfl_xor(val, 1, 64);
        if (!(v & 1))
            Vfpb[((size_t)bt * 1024 + tc) * 16 + (v >> 1)] = packbf(val, other);
    } else if (MODE == 1) {
        float val = Vfp32[vidx] + acc * scale;
        Vfp32[vidx] = val;
        float other = __shfl_xor(val, 1, 64);
        if (!(v & 1))
            Vfpb[((size_t)bt * 1024 + tc) * 16 + (v >> 1)] = packbf(val, other);
    } else {
        float val = acc * scale;
        const int b = bt * 32 + (tc & 31);
        const int o = (tc >> 6) * 4 + (v >> 4) * 2 + ((v >> 3) & 1);
        const int k = (v & 3) + 8 * ((v >> 2) & 1) + 4 * w5;
        out[((size_t)b * 64 + o) * 16 + k] = val;
    }
}

// ------------------------- round-5 fallback (small ws, proven) -------------------------
#define FTI 18
#define FNCH 64

__device__ __forceinline__ void load_lds16(const float4* gp, float4* lp) {
    __builtin_amdgcn_global_load_lds((gu32*)gp, (lu32*)lp, 16, 0, 0);
}
__device__ __forceinline__ float rfl(float v) {
    return __builtin_bit_cast(float, __builtin_amdgcn_readfirstlane(__builtin_bit_cast(int, v)));
}

template<bool UNIFORM>
__global__ __launch_bounds__(256, 2)
void caps_route_fb(const float* __restrict__ x, const float* __restrict__ W,
                   const float* __restrict__ Vsum, float* __restrict__ s_out) {
    __shared__ float4 wlds[2][2048];
    __shared__ float4 xlds[8 * FTI * 2];
    const int t = threadIdx.x;
    const int w = t >> 6, o = t & 63;
    const int chunk = blockIdx.x % FNCH, bblk = blockIdx.x / FNCH;
    const int i0 = chunk * FTI, bbase = bblk * 8 + w * 2;
    const float4* __restrict__ xg = (const float4*)x;
    const float4* __restrict__ Wg = (const float4*)W;
    for (int e = t; e < 8 * FTI * 2; e += 256) {
        int bb = e / (FTI * 2), r = e % (FTI * 2);
        xlds[e] = xg[((bblk * 8 + bb) * 1152 + i0 + (r >> 1)) * 2 + (r & 1)];
    }
    const float4* wsrc = Wg + (size_t)o * 36864 + (size_t)i0 * 32 + w * 8;
    #pragma unroll
    for (int r = 0; r < 8; ++r) load_lds16(wsrc + r, &wlds[0][(w * 8 + r) * 64]);
    float vsf[2][16];
    if (!UNIFORM) {
        const float4* vg = (const float4*)Vsum;
        #pragma unroll
        for (int ll = 0; ll < 2; ++ll)
            #pragma unroll
            for (int q = 0; q < 4; ++q) {
                float4 v = vg[((size_t)(bbase + ll) * 64 + o) * 4 + q];
                vsf[ll][q*4+0] = v.x; vsf[ll][q*4+1] = v.y;
                vsf[ll][q*4+2] = v.z; vsf[ll][q*4+3] = v.w;
            }
    }
    float sacc[2][16];
    #pragma unroll
    for (int ll = 0; ll < 2; ++ll)
        #pragma unroll
        for (int k = 0; k < 16; ++k) sacc[ll][k] = 0.0f;
    for (int ii = 0; ii < FTI; ++ii) {
        const int cur = ii & 1;
        __syncthreads();
        if (ii + 1 < FTI) {
            const float4* ws = wsrc + (size_t)(ii + 1) * 32;
            #pragma unroll
            for (int r = 0; r < 8; ++r) load_lds16(ws + r, &wlds[cur ^ 1][(w * 8 + r) * 64]);
        }
        float4 A0 = xlds[(w*2+0)*(FTI*2) + ii*2 + 0];
        float4 B0 = xlds[(w*2+0)*(FTI*2) + ii*2 + 1];
        float4 A1 = xlds[(w*2+1)*(FTI*2) + ii*2 + 0];
        float4 B1 = xlds[(w*2+1)*(FTI*2) + ii*2 + 1];
        float xa0x=rfl(A0.x),xa0y=rfl(A0.y),xa0z=rfl(A0.z),xa0w=rfl(A0.w);
        float xb0x=rfl(B0.x),xb0y=rfl(B0.y),xb0z=rfl(B0.z),xb0w=rfl(B0.w);
        float xa1x=rfl(A1.x),xa1y=rfl(A1.y),xa1z=rfl(A1.z),xa1w=rfl(A1.w);
        float xb1x=rfl(B1.x),xb1y=rfl(B1.y),xb1z=rfl(B1.z),xb1w=rfl(B1.w);
        const float4* wb = wlds[cur];
        float u[2][16];
        float logit0 = 0.0f, logit1 = 0.0f;
        #pragma unroll
        for (int k = 0; k < 16; ++k) {
            float4 w0 = wb[(2*k  )*64 + o];
            float4 w1 = wb[(2*k+1)*64 + o];
            float uk0 = w0.x*xa0x; uk0=fmaf(w0.y,xa0y,uk0); uk0=fmaf(w0.z,xa0z,uk0);
            uk0=fmaf(w0.w,xa0w,uk0); uk0=fmaf(w1.x,xb0x,uk0); uk0=fmaf(w1.y,xb0y,uk0);
            uk0=fmaf(w1.z,xb0z,uk0); uk0=fmaf(w1.w,xb0w,uk0);
            float uk1 = w0.x*xa1x; uk1=fmaf(w0.y,xa1y,uk1); uk1=fmaf(w0.z,xa1z,uk1);
            uk1=fmaf(w0.w,xa1w,uk1); uk1=fmaf(w1.x,xb1x,uk1); uk1=fmaf(w1.y,xb1y,uk1);
            uk1=fmaf(w1.z,xb1z,uk1); uk1=fmaf(w1.w,xb1w,uk1);
            u[0][k]=uk0; u[1][k]=uk1;
            if (!UNIFORM) { logit0=fmaf(vsf[0][k],uk0,logit0); logit1=fmaf(vsf[1][k],uk1,logit1); }
        }
        float c0, c1;
        if (UNIFORM) { c0 = c1 = 1.0f/64.0f; }
        else {
            float m0=logit0, m1=logit1;
            #pragma unroll
            for (int d=32; d>=1; d>>=1) { m0=fmaxf(m0,__shfl_xor(m0,d,64)); m1=fmaxf(m1,__shfl_xor(m1,d,64)); }
            float e0=__expf(logit0-m0), e1=__expf(logit1-m1);
            float s0=e0, s1=e1;
            #pragma unroll
            for (int d=32; d>=1; d>>=1) { s0+=__shfl_xor(s0,d,64); s1+=__shfl_xor(s1,d,64); }
            c0=e0/s0; c1=e1/s1;
        }
        #pragma unroll
        for (int k = 0; k < 16; ++k) {
            sacc[0][k]=fmaf(c0,u[0][k],sacc[0][k]);
            sacc[1][k]=fmaf(c1,u[1][k],sacc[1][k]);
        }
    }
    #pragma unroll
    for (int ll = 0; ll < 2; ++ll) {
        float4* sp = (float4*)s_out + (((size_t)chunk * 64 + (bbase + ll)) * 64 + o) * 4;
        sp[0]=make_float4(sacc[ll][0],sacc[ll][1],sacc[ll][2],sacc[ll][3]);
        sp[1]=make_float4(sacc[ll][4],sacc[ll][5],sacc[ll][6],sacc[ll][7]);
        sp[2]=make_float4(sacc[ll][8],sacc[ll][9],sacc[ll][10],sacc[ll][11]);
        sp[3]=make_float4(sacc[ll][12],sacc[ll][13],sacc[ll][14],sacc[ll][15]);
    }
}

template<int MODE>
__global__ __launch_bounds__(256)
void reduce_squash_fb(const float* __restrict__ sp, float* __restrict__ Vs, float* __restrict__ out) {
    const int t = threadIdx.x;
    const int p = t >> 4, q = t & 15;
    const int pair = blockIdx.x * 16 + p;
    const int b = pair >> 6, o = pair & 63;
    float acc[16];
    #pragma unroll
    for (int k = 0; k < 16; ++k) acc[k] = 0.0f;
    const float4* base = (const float4*)sp;
    for (int c = q * (FNCH/16); c < (q + 1) * (FNCH/16); ++c) {
        const float4* pptr = base + (((size_t)c * 64 + b) * 64 + o) * 4;
        float4 v0=pptr[0],v1=pptr[1],v2=pptr[2],v3=pptr[3];
        acc[0]+=v0.x;acc[1]+=v0.y;acc[2]+=v0.z;acc[3]+=v0.w;
        acc[4]+=v1.x;acc[5]+=v1.y;acc[6]+=v1.z;acc[7]+=v1.w;
        acc[8]+=v2.x;acc[9]+=v2.y;acc[10]+=v2.z;acc[11]+=v2.w;
        acc[12]+=v3.x;acc[13]+=v3.y;acc[14]+=v3.z;acc[15]+=v3.w;
    }
    #pragma unroll
    for (int d = 1; d < 16; d <<= 1)
        #pragma unroll
        for (int k = 0; k < 16; ++k) acc[k] += __shfl_xor(acc[k], d, 64);
    if (q == 0) {
        float n2 = 0.0f;
        #pragma unroll
        for (int k = 0; k < 16; ++k) n2 = fmaf(acc[k], acc[k], n2);
        const float scale = n2 / (1.0f + n2) / sqrtf(n2 + 1e-7f);
        if (MODE == 0) {
            float4* vf = (float4*)Vs + (size_t)pair * 4;
            #pragma unroll
            for (int r = 0; r < 4; ++r)
                vf[r] = make_float4(scale*acc[r*4+0],scale*acc[r*4+1],scale*acc[r*4+2],scale*acc[r*4+3]);
        } else if (MODE == 1) {
            float4* vf = (float4*)Vs + (size_t)pair * 4;
            #pragma unroll
            for (int r = 0; r < 4; ++r) {
                float4 v = vf[r];
                v.x=fmaf(scale,acc[r*4+0],v.x); v.y=fmaf(scale,acc[r*4+1],v.y);
                v.z=fmaf(scale,acc[r*4+2],v.z); v.w=fmaf(scale,acc[r*4+3],v.w);
                vf[r] = v;
            }
        } else {
            float4* of = (float4*)out + (size_t)pair * 4;
            #pragma unroll
            for (int r = 0; r < 4; ++r)
                of[r] = make_float4(scale*acc[r*4+0],scale*acc[r*4+1],scale*acc[r*4+2],scale*acc[r*4+3]);
        }
    }
}
// -----------------------------------------------------------------------------

extern "C" void kernel_launch(void* const* d_in, const int* in_sizes, int n_in,
                              void* d_out, int out_size, void* d_ws, size_t ws_size,
                              hipStream_t stream) {
    const float* x = (const float*)d_in[0];   // [64,1152,8]
    const float* W = (const float*)d_in[1];   // [64,1152,16,8]
    float* out = (float*)d_out;               // [64,64,16]

    float* Vfp32 = (float*)d_ws;                                     // 65536 f32
    unsigned int* Vfpb = (unsigned int*)(Vfp32 + 65536);             // 32768 u32
    unsigned short* spart = (unsigned short*)(Vfpb + 32768);         // 128*65536 bf16
    unsigned short* Wp = spart + (size_t)CNCH * 65536;               // 9.4M bf16
    unsigned short* xpp = Wp + (size_t)1152 * 64 * 16 * 8;           // 1.18M bf16
    const size_t need_full = (size_t)65536 * 4 + (size_t)32768 * 4
        + ((size_t)CNCH * 65536 + (size_t)1152 * 64 * 16 * 8 + (size_t)1152 * 2 * 512) * 2;

    if (ws_size >= need_full) {
        xform<<<4608 + 288, 256, 0, stream>>>(W, x, Wp, xpp);
        caps32<0><<<256, 1024, 0, stream>>>(Wp, xpp, Vfpb, spart);
        reduce32<0><<<256, 256, 0, stream>>>(spart, Vfp32, Vfpb, out);
        caps32<1><<<256, 1024, 0, stream>>>(Wp, xpp, Vfpb, spart);
        reduce32<1><<<256, 256, 0, stream>>>(spart, Vfp32, Vfpb, out);
        caps32<1><<<256, 1024, 0, stream>>>(Wp, xpp, Vfpb, spart);
        reduce32<2><<<256, 256, 0, stream>>>(spart, Vfp32, Vfpb, out);
    } else {
        // proven round-5 path (needs ~17 MB)
        float* Vs = (float*)d_ws;
        float* sp = Vs + 65536;
        dim3 grid(8 * FNCH), blk(256);
        dim3 rg(256), rb(256);
        caps_route_fb<true ><<<grid, blk, 0, stream>>>(x, W, nullptr, sp);
        reduce_squash_fb<0><<<rg, rb, 0, stream>>>(sp, Vs, out);
        caps_route_fb<false><<<grid, blk, 0, stream>>>(x, W, Vs, sp);
        reduce_squash_fb<1><<<rg, rb, 0, stream>>>(sp, Vs, out);
        caps_route_fb<false><<<grid, blk, 0, stream>>>(x, W, Vs, sp);
        reduce_squash_fb<2><<<rg, rb, 0, stream>>>(sp, Vs, out);
    }
}

// Round 14
// 91.555 us; speedup vs baseline: 5.9305x; 5.9305x over previous
//
#include <hip/hip_runtime.h>
#include <math.h>

// B=64, N_in=1152, K_in=8, N_out=64, K_out=16, ITER=3
// MFMA path (round-11 structure): u-tiles C[k,b] via 16x16x32 bf16 MFMA, fp32
// fidelity from (hi,lo)x(hi,lo) K-slot pack. 1024-thread blocks (16 waves,
// 4 o/wave); 2 i-slices per LDS step -> 9 barriers/pass; bf16 partials.
// FIX vs round 11: __launch_bounds__(1024, 4) -> 128-VGPR cap (was (1024,1)
// which capped at 64 VGPRs and silently spilled; evidence: r9 (512,4)->128,
// r12/r13 (1024,1)->64).

#define CTI 18        // i per chunk
#define IPB 2         // i per buffer step
#define NSTEP 9       // CTI / IPB
#define CNCH 64       // 1152 / CTI

typedef __attribute__((ext_vector_type(8))) short short8v;
typedef __attribute__((ext_vector_type(8))) unsigned short ushort8v;
typedef __attribute__((ext_vector_type(4))) float f32x4;

typedef const __attribute__((address_space(1))) unsigned int gu32;
typedef __attribute__((address_space(3))) unsigned int lu32;

__device__ __forceinline__ unsigned short f2bf(float f) {   // RTNE
    unsigned u = __builtin_bit_cast(unsigned, f);
    u = u + 0x7FFFu + ((u >> 16) & 1u);
    return (unsigned short)(u >> 16);
}
__device__ __forceinline__ float bf2f(unsigned short h) {
    unsigned u = ((unsigned)h) << 16;
    return __builtin_bit_cast(float, u);
}
__device__ __forceinline__ float lo16f(unsigned u) {
    return __builtin_bit_cast(float, u << 16);
}
__device__ __forceinline__ float hi16f(unsigned u) {
    return __builtin_bit_cast(float, u & 0xFFFF0000u);
}

// W[o][i][k][j] f32 -> Wp[i][o][p][k][j] bf16 ; x[b][i][j] f32 -> xp[i][p][b][j] bf16
__global__ __launch_bounds__(256)
void xform(const float* __restrict__ W, const float* __restrict__ x,
           unsigned short* __restrict__ Wp, unsigned short* __restrict__ xpp) {
    const int bid = blockIdx.x;
    if (bid < 4608) {
        int tid = bid * 256 + threadIdx.x;          // 1152*64*16
        int k = tid & 15, o = (tid >> 4) & 63, i = tid >> 10;
        const float4* src = (const float4*)(W + (((size_t)o * 1152 + i) * 16 + k) * 8);
        float4 v0 = src[0], v1 = src[1];
        float vf[8] = {v0.x, v0.y, v0.z, v0.w, v1.x, v1.y, v1.z, v1.w};
        ushort8v hi, lo;
        #pragma unroll
        for (int j = 0; j < 8; ++j) {
            unsigned short h = f2bf(vf[j]);
            hi[j] = h;
            lo[j] = f2bf(vf[j] - bf2f(h));
        }
        size_t base = (((size_t)i * 64 + o) * 2) * 128 + (size_t)k * 8;
        *reinterpret_cast<ushort8v*>(Wp + base)       = hi;
        *reinterpret_cast<ushort8v*>(Wp + base + 128) = lo;
    } else {
        int tid = (bid - 4608) * 256 + threadIdx.x; // 1152*64
        int b = tid & 63, i = tid >> 6;
        const float4* src = (const float4*)(x + ((size_t)b * 1152 + i) * 8);
        float4 v0 = src[0], v1 = src[1];
        float vf[8] = {v0.x, v0.y, v0.z, v0.w, v1.x, v1.y, v1.z, v1.w};
        ushort8v hi, lo;
        #pragma unroll
        for (int j = 0; j < 8; ++j) {
            unsigned short h = f2bf(vf[j]);
            hi[j] = h;
            lo[j] = f2bf(vf[j] - bf2f(h));
        }
        size_t base = ((size_t)i * 2) * 512 + (size_t)b * 8;
        *reinterpret_cast<ushort8v*>(xpp + base)       = hi;
        *reinterpret_cast<ushort8v*>(xpp + base + 512) = lo;
    }
}

// Routing pass. Grid 256 = btile(4) x chunk(64); btile-sharers of a chunk
// differ by 64 in blockIdx -> same XCD L2. Block: 1024 thr = 16 waves;
// wave wv owns o = wv*4..+4; lanes: col b = l&15, k-group g = l>>4.
// Wp staged 2 i-slices (64 KB) per step, double-buffered; ONE barrier/step.
template<int ROUTED>
__global__ __launch_bounds__(1024, 4)   // 4 waves/EU -> 128-VGPR cap (no spill)
void caps_mfma(const unsigned short* __restrict__ Wp,
               const unsigned short* __restrict__ xp,
               const float* __restrict__ Vfp,
               unsigned short* __restrict__ spart) {
    __shared__ unsigned short wlds[2][IPB * 16384];   // 2 x 64 KB
    __shared__ float zbuf[2][IPB][256];               // [step parity][sub-i][wave*16+b15]

    const int t = threadIdx.x;
    const int wv = t >> 6, l = t & 63;
    const int btile = blockIdx.x >> 6, chunk = blockIdx.x & 63;
    const int g = l >> 4, b15 = l & 15;
    const int o0 = wv * 4;
    const int i0 = chunk * CTI;

    // Vsum packed to bf16 pairs: 8 VGPRs
    uint2 vpk[4];
    if (ROUTED) {
        #pragma unroll
        for (int oo = 0; oo < 4; ++oo) {
            f32x4 Vf = *reinterpret_cast<const f32x4*>(
                Vfp + (((size_t)btile * 64 + o0 + oo) * 64 + l) * 4);
            vpk[oo].x = (unsigned)f2bf(Vf[0]) | ((unsigned)f2bf(Vf[1]) << 16);
            vpk[oo].y = (unsigned)f2bf(Vf[2]) | ((unsigned)f2bf(Vf[3]) << 16);
        }
    }

    f32x4 s[4];
    #pragma unroll
    for (int oo = 0; oo < 4; ++oo) s[oo] = (f32x4){0.f, 0.f, 0.f, 0.f};

    // DMA IPB consecutive i-slices (64 KB): 4 rounds x 16 waves x 64 lanes x 16 B
    #define STAGE2(buf, ibase)                                                    \
    {                                                                             \
        const ushort8v* srcb = reinterpret_cast<const ushort8v*>(                 \
            Wp + (size_t)(ibase) * 16384);                                        \
        _Pragma("unroll")                                                         \
        for (int r = 0; r < 4; ++r)                                               \
            __builtin_amdgcn_global_load_lds(                                     \
                (gu32*)(srcb + (r * 1024 + wv * 64 + l)),                         \
                (lu32*)&wlds[buf][(size_t)(r * 1024 + wv * 64) * 8], 16, 0, 0);   \
    }

    #define LOADB(i) (*reinterpret_cast<const short8v*>(                          \
        xp + (((size_t)(i) * 2 + (l >> 5)) * 64 + btile * 16 + b15) * 8))

    STAGE2(0, i0);
    short8v Bf0 = LOADB(i0);
    short8v Bf1 = LOADB(i0 + 1);
    __syncthreads();   // prologue DMA complete

    int cur = 0;
    for (int st = 0; st < NSTEP; ++st) {
        // prefetch next 2 slices; DMA drains at this step's single barrier
        short8v Bn0 = Bf0, Bn1 = Bf1;
        if (st + 1 < NSTEP) {
            STAGE2(cur ^ 1, i0 + (st + 1) * IPB);
            Bn0 = LOADB(i0 + (st + 1) * IPB);
            Bn1 = LOADB(i0 + (st + 1) * IPB + 1);
        }

        if (!ROUTED) {
            #pragma unroll
            for (int oo = 0; oo < 4; ++oo) {
                short8v Af0 = *reinterpret_cast<const short8v*>(
                    &wlds[cur][0] + (((o0 + oo) * 2 + (g & 1)) * 128 + b15 * 8));
                s[oo] = __builtin_amdgcn_mfma_f32_16x16x32_bf16(Af0, Bf0, s[oo], 0, 0, 0);
                short8v Af1 = *reinterpret_cast<const short8v*>(
                    &wlds[cur][16384] + (((o0 + oo) * 2 + (g & 1)) * 128 + b15 * 8));
                s[oo] = __builtin_amdgcn_mfma_f32_16x16x32_bf16(Af1, Bf1, s[oo], 0, 0, 0);
            }
            __syncthreads();   // DMA(next) complete + buffer-reuse safety
        } else {
            f32x4 u[IPB][4];
            float lg[IPB][4];
            float Zp0 = 0.f, Zp1 = 0.f;
            #pragma unroll
            for (int oo = 0; oo < 4; ++oo) {
                short8v Af0 = *reinterpret_cast<const short8v*>(
                    &wlds[cur][0] + (((o0 + oo) * 2 + (g & 1)) * 128 + b15 * 8));
                f32x4 zz = {0.f, 0.f, 0.f, 0.f};
                u[0][oo] = __builtin_amdgcn_mfma_f32_16x16x32_bf16(Af0, Bf0, zz, 0, 0, 0);
                short8v Af1 = *reinterpret_cast<const short8v*>(
                    &wlds[cur][16384] + (((o0 + oo) * 2 + (g & 1)) * 128 + b15 * 8));
                u[1][oo] = __builtin_amdgcn_mfma_f32_16x16x32_bf16(Af1, Bf1, zz, 0, 0, 0);

                float p0 = u[0][oo][0] * lo16f(vpk[oo].x);
                p0 = fmaf(u[0][oo][1], hi16f(vpk[oo].x), p0);
                p0 = fmaf(u[0][oo][2], lo16f(vpk[oo].y), p0);
                p0 = fmaf(u[0][oo][3], hi16f(vpk[oo].y), p0);
                float p1 = u[1][oo][0] * lo16f(vpk[oo].x);
                p1 = fmaf(u[1][oo][1], hi16f(vpk[oo].x), p1);
                p1 = fmaf(u[1][oo][2], lo16f(vpk[oo].y), p1);
                p1 = fmaf(u[1][oo][3], hi16f(vpk[oo].y), p1);
                p0 += __shfl_xor(p0, 16, 64);  p1 += __shfl_xor(p1, 16, 64);
                p0 += __shfl_xor(p0, 32, 64);  p1 += __shfl_xor(p1, 32, 64);
                // logits bounded (|logit| <= ~1.2): exp without max-subtraction
                float e0 = __expf(p0), e1 = __expf(p1);
                lg[0][oo] = e0; lg[1][oo] = e1;
                Zp0 += e0; Zp1 += e1;
            }
            if (l < 16) {
                zbuf[st & 1][0][wv * 16 + l] = Zp0;
                zbuf[st & 1][1][wv * 16 + l] = Zp1;
            }
            __syncthreads();                   // Z visible; DMA(next) drained
            float Z0 = zbuf[st & 1][0][b15];
            float Z1 = zbuf[st & 1][1][b15];
            #pragma unroll
            for (int w2 = 1; w2 < 16; ++w2) {
                Z0 += zbuf[st & 1][0][w2 * 16 + b15];
                Z1 += zbuf[st & 1][1][w2 * 16 + b15];
            }
            float rz0 = 1.0f / Z0, rz1 = 1.0f / Z1;
            #pragma unroll
            for (int oo = 0; oo < 4; ++oo) {
                float c0 = lg[0][oo] * rz0;
                float c1 = lg[1][oo] * rz1;
                s[oo][0] = fmaf(c0, u[0][oo][0], fmaf(c1, u[1][oo][0], s[oo][0]));
                s[oo][1] = fmaf(c0, u[0][oo][1], fmaf(c1, u[1][oo][1], s[oo][1]));
                s[oo][2] = fmaf(c0, u[0][oo][2], fmaf(c1, u[1][oo][2], s[oo][2]));
                s[oo][3] = fmaf(c0, u[0][oo][3], fmaf(c1, u[1][oo][3], s[oo][3]));
            }
        }
        Bf0 = Bn0; Bf1 = Bn1;
        cur ^= 1;
    }

    // bf16 partials: [chunk][btile][o][l][4k], 8 B/lane coalesced
    const float fin = ROUTED ? 1.0f : (1.0f / 64.0f);
    #pragma unroll
    for (int oo = 0; oo < 4; ++oo) {
        f32x4 vv = s[oo] * fin;
        uint2 pk;
        pk.x = (unsigned)f2bf(vv[0]) | ((unsigned)f2bf(vv[1]) << 16);
        pk.y = (unsigned)f2bf(vv[2]) | ((unsigned)f2bf(vv[3]) << 16);
        *reinterpret_cast<uint2*>(spart +
            ((((size_t)chunk * 4 + btile) * 64 + (o0 + oo)) * 64 + l) * 4) = pk;
    }
    #undef STAGE2
    #undef LOADB
}

// Sum CNCH bf16 chunk-partials, squash, update Vfp / write out.
// Grid 256 blocks (one (btile,o) pair) x 256 thr: l = t&63, cq = t>>6.
template<int MODE>
__global__ __launch_bounds__(256)
void reduce2(const unsigned short* __restrict__ spart, float* __restrict__ Vfp,
             float* __restrict__ out) {
    __shared__ f32x4 red[256];
    const int t = threadIdx.x;
    const int l = t & 63, cq = t >> 6;
    const int pair = blockIdx.x;               // btile*64 + o
    const int btile = pair >> 6, o = pair & 63;

    f32x4 acc = {0.f, 0.f, 0.f, 0.f};
    const unsigned short* base = spart + (((size_t)btile * 64 + o) * 64 + l) * 4;
    for (int c = cq * (CNCH/4); c < (cq + 1) * (CNCH/4); ++c) {
        uint2 w = *reinterpret_cast<const uint2*>(base + (size_t)c * 65536);
        acc[0] += lo16f(w.x); acc[1] += hi16f(w.x);
        acc[2] += lo16f(w.y); acc[3] += hi16f(w.y);
    }
    red[t] = acc;
    __syncthreads();
    if (cq == 0) {
        acc = red[l] + red[64 + l] + red[128 + l] + red[192 + l];
        float n2 = acc[0]*acc[0] + acc[1]*acc[1] + acc[2]*acc[2] + acc[3]*acc[3];
        n2 += __shfl_xor(n2, 16, 64);
        n2 += __shfl_xor(n2, 32, 64);
        const float scale = n2 / (1.0f + n2) / sqrtf(n2 + 1e-7f);
        f32x4 v = acc * scale;
        float* vp = Vfp + (((size_t)btile * 64 + o) * 64 + l) * 4;
        if (MODE == 0) {
            *reinterpret_cast<f32x4*>(vp) = v;
        } else if (MODE == 1) {
            f32x4 old = *reinterpret_cast<const f32x4*>(vp);
            *reinterpret_cast<f32x4*>(vp) = old + v;
        } else {
            const int b = btile * 16 + (l & 15), gq = l >> 4;
            *reinterpret_cast<f32x4*>(out + (((size_t)b * 64 + o) * 16 + gq * 4)) = v;
        }
    }
}

// ------------------------- round-5 fallback (small ws, proven) -------------------------
#define FTI 18
#define FNCH 64

__device__ __forceinline__ void load_lds16(const float4* gp, float4* lp) {
    __builtin_amdgcn_global_load_lds((gu32*)gp, (lu32*)lp, 16, 0, 0);
}
__device__ __forceinline__ float rfl(float v) {
    return __builtin_bit_cast(float, __builtin_amdgcn_readfirstlane(__builtin_bit_cast(int, v)));
}

template<bool UNIFORM>
__global__ __launch_bounds__(256, 2)
void caps_route_fb(const float* __restrict__ x, const float* __restrict__ W,
                   const float* __restrict__ Vsum, float* __restrict__ s_out) {
    __shared__ float4 wlds[2][2048];
    __shared__ float4 xlds[8 * FTI * 2];
    const int t = threadIdx.x;
    const int w = t >> 6, o = t & 63;
    const int chunk = blockIdx.x % FNCH, bblk = blockIdx.x / FNCH;
    const int i0 = chunk * FTI, bbase = bblk * 8 + w * 2;
    const float4* __restrict__ xg = (const float4*)x;
    const float4* __restrict__ Wg = (const float4*)W;
    for (int e = t; e < 8 * FTI * 2; e += 256) {
        int bb = e / (FTI * 2), r = e % (FTI * 2);
        xlds[e] = xg[((bblk * 8 + bb) * 1152 + i0 + (r >> 1)) * 2 + (r & 1)];
    }
    const float4* wsrc = Wg + (size_t)o * 36864 + (size_t)i0 * 32 + w * 8;
    #pragma unroll
    for (int r = 0; r < 8; ++r) load_lds16(wsrc + r, &wlds[0][(w * 8 + r) * 64]);
    float vsf[2][16];
    if (!UNIFORM) {
        const float4* vg = (const float4*)Vsum;
        #pragma unroll
        for (int ll = 0; ll < 2; ++ll)
            #pragma unroll
            for (int q = 0; q < 4; ++q) {
                float4 v = vg[((size_t)(bbase + ll) * 64 + o) * 4 + q];
                vsf[ll][q*4+0] = v.x; vsf[ll][q*4+1] = v.y;
                vsf[ll][q*4+2] = v.z; vsf[ll][q*4+3] = v.w;
            }
    }
    float sacc[2][16];
    #pragma unroll
    for (int ll = 0; ll < 2; ++ll)
        #pragma unroll
        for (int k = 0; k < 16; ++k) sacc[ll][k] = 0.0f;
    for (int ii = 0; ii < FTI; ++ii) {
        const int cur = ii & 1;
        __syncthreads();
        if (ii + 1 < FTI) {
            const float4* ws = wsrc + (size_t)(ii + 1) * 32;
            #pragma unroll
            for (int r = 0; r < 8; ++r) load_lds16(ws + r, &wlds[cur ^ 1][(w * 8 + r) * 64]);
        }
        float4 A0 = xlds[(w*2+0)*(FTI*2) + ii*2 + 0];
        float4 B0 = xlds[(w*2+0)*(FTI*2) + ii*2 + 1];
        float4 A1 = xlds[(w*2+1)*(FTI*2) + ii*2 + 0];
        float4 B1 = xlds[(w*2+1)*(FTI*2) + ii*2 + 1];
        float xa0x=rfl(A0.x),xa0y=rfl(A0.y),xa0z=rfl(A0.z),xa0w=rfl(A0.w);
        float xb0x=rfl(B0.x),xb0y=rfl(B0.y),xb0z=rfl(B0.z),xb0w=rfl(B0.w);
        float xa1x=rfl(A1.x),xa1y=rfl(A1.y),xa1z=rfl(A1.z),xa1w=rfl(A1.w);
        float xb1x=rfl(B1.x),xb1y=rfl(B1.y),xb1z=rfl(B1.z),xb1w=rfl(B1.w);
        const float4* wb = wlds[cur];
        float u[2][16];
        float logit0 = 0.0f, logit1 = 0.0f;
        #pragma unroll
        for (int k = 0; k < 16; ++k) {
            float4 w0 = wb[(2*k  )*64 + o];
            float4 w1 = wb[(2*k+1)*64 + o];
            float uk0 = w0.x*xa0x; uk0=fmaf(w0.y,xa0y,uk0); uk0=fmaf(w0.z,xa0z,uk0);
            uk0=fmaf(w0.w,xa0w,uk0); uk0=fmaf(w1.x,xb0x,uk0); uk0=fmaf(w1.y,xb0y,uk0);
            uk0=fmaf(w1.z,xb0z,uk0); uk0=fmaf(w1.w,xb0w,uk0);
            float uk1 = w0.x*xa1x; uk1=fmaf(w0.y,xa1y,uk1); uk1=fmaf(w0.z,xa1z,uk1);
            uk1=fmaf(w0.w,xa1w,uk1); uk1=fmaf(w1.x,xb1x,uk1); uk1=fmaf(w1.y,xb1y,uk1);
            uk1=fmaf(w1.z,xb1z,uk1); uk1=fmaf(w1.w,xb1w,uk1);
            u[0][k]=uk0; u[1][k]=uk1;
            if (!UNIFORM) { logit0=fmaf(vsf[0][k],uk0,logit0); logit1=fmaf(vsf[1][k],uk1,logit1); }
        }
        float c0, c1;
        if (UNIFORM) { c0 = c1 = 1.0f/64.0f; }
        else {
            float m0=logit0, m1=logit1;
            #pragma unroll
            for (int d=32; d>=1; d>>=1) { m0=fmaxf(m0,__shfl_xor(m0,d,64)); m1=fmaxf(m1,__shfl_xor(m1,d,64)); }
            float e0=__expf(logit0-m0), e1=__expf(logit1-m1);
            float s0=e0, s1=e1;
            #pragma unroll
            for (int d=32; d>=1; d>>=1) { s0+=__shfl_xor(s0,d,64); s1+=__shfl_xor(s1,d,64); }
            c0=e0/s0; c1=e1/s1;
        }
        #pragma unroll
        for (int k = 0; k < 16; ++k) {
            sacc[0][k]=fmaf(c0,u[0][k],sacc[0][k]);
            sacc[1][k]=fmaf(c1,u[1][k],sacc[1][k]);
        }
    }
    #pragma unroll
    for (int ll = 0; ll < 2; ++ll) {
        float4* sp = (float4*)s_out + (((size_t)chunk * 64 + (bbase + ll)) * 64 + o) * 4;
        sp[0]=make_float4(sacc[ll][0],sacc[ll][1],sacc[ll][2],sacc[ll][3]);
        sp[1]=make_float4(sacc[ll][4],sacc[ll][5],sacc[ll][6],sacc[ll][7]);
        sp[2]=make_float4(sacc[ll][8],sacc[ll][9],sacc[ll][10],sacc[ll][11]);
        sp[3]=make_float4(sacc[ll][12],sacc[ll][13],sacc[ll][14],sacc[ll][15]);
    }
}

template<int MODE>
__global__ __launch_bounds__(256)
void reduce_squash_fb(const float* __restrict__ sp, float* __restrict__ Vs, float* __restrict__ out) {
    const int t = threadIdx.x;
    const int p = t >> 4, q = t & 15;
    const int pair = blockIdx.x * 16 + p;
    const int b = pair >> 6, o = pair & 63;
    float acc[16];
    #pragma unroll
    for (int k = 0; k < 16; ++k) acc[k] = 0.0f;
    const float4* base = (const float4*)sp;
    for (int c = q * (FNCH/16); c < (q + 1) * (FNCH/16); ++c) {
        const float4* pptr = base + (((size_t)c * 64 + b) * 64 + o) * 4;
        float4 v0=pptr[0],v1=pptr[1],v2=pptr[2],v3=pptr[3];
        acc[0]+=v0.x;acc[1]+=v0.y;acc[2]+=v0.z;acc[3]+=v0.w;
        acc[4]+=v1.x;acc[5]+=v1.y;acc[6]+=v1.z;acc[7]+=v1.w;
        acc[8]+=v2.x;acc[9]+=v2.y;acc[10]+=v2.z;acc[11]+=v2.w;
        acc[12]+=v3.x;acc[13]+=v3.y;acc[14]+=v3.z;acc[15]+=v3.w;
    }
    #pragma unroll
    for (int d = 1; d < 16; d <<= 1)
        #pragma unroll
        for (int k = 0; k < 16; ++k) acc[k] += __shfl_xor(acc[k], d, 64);
    if (q == 0) {
        float n2 = 0.0f;
        #pragma unroll
        for (int k = 0; k < 16; ++k) n2 = fmaf(acc[k], acc[k], n2);
        const float scale = n2 / (1.0f + n2) / sqrtf(n2 + 1e-7f);
        if (MODE == 0) {
            float4* vf = (float4*)Vs + (size_t)pair * 4;
            #pragma unroll
            for (int r = 0; r < 4; ++r)
                vf[r] = make_float4(scale*acc[r*4+0],scale*acc[r*4+1],scale*acc[r*4+2],scale*acc[r*4+3]);
        } else if (MODE == 1) {
            float4* vf = (float4*)Vs + (size_t)pair * 4;
            #pragma unroll
            for (int r = 0; r < 4; ++r) {
                float4 v = vf[r];
                v.x=fmaf(scale,acc[r*4+0],v.x); v.y=fmaf(scale,acc[r*4+1],v.y);
                v.z=fmaf(scale,acc[r*4+2],v.z); v.w=fmaf(scale,acc[r*4+3],v.w);
                vf[r] = v;
            }
        } else {
            float4* of = (float4*)out + (size_t)pair * 4;
            #pragma unroll
            for (int r = 0; r < 4; ++r)
                of[r] = make_float4(scale*acc[r*4+0],scale*acc[r*4+1],scale*acc[r*4+2],scale*acc[r*4+3]);
        }
    }
}
// -----------------------------------------------------------------------------

extern "C" void kernel_launch(void* const* d_in, const int* in_sizes, int n_in,
                              void* d_out, int out_size, void* d_ws, size_t ws_size,
                              hipStream_t stream) {
    const float* x = (const float*)d_in[0];   // [64,1152,8]
    const float* W = (const float*)d_in[1];   // [64,1152,16,8]
    float* out = (float*)d_out;               // [64,64,16]

    float* Vfp = (float*)d_ws;                                       // 65536 f32
    unsigned short* spart = (unsigned short*)(Vfp + 65536);          // CNCH*65536 bf16
    unsigned short* Wp = spart + (size_t)CNCH * 65536;
    unsigned short* xpp = Wp + (size_t)1152 * 64 * 256;
    const size_t need_full = (size_t)65536 * 4
        + ((size_t)CNCH * 65536 + (size_t)1152 * 64 * 256 + (size_t)1152 * 2 * 512) * 2;

    if (ws_size >= need_full) {
        xform<<<4608 + 288, 256, 0, stream>>>(W, x, Wp, xpp);
        caps_mfma<0><<<256, 1024, 0, stream>>>(Wp, xpp, Vfp, spart);
        reduce2<0><<<256, 256, 0, stream>>>(spart, Vfp, out);
        caps_mfma<1><<<256, 1024, 0, stream>>>(Wp, xpp, Vfp, spart);
        reduce2<1><<<256, 256, 0, stream>>>(spart, Vfp, out);
        caps_mfma<1><<<256, 1024, 0, stream>>>(Wp, xpp, Vfp, spart);
        reduce2<2><<<256, 256, 0, stream>>>(spart, Vfp, out);
    } else {
        // proven round-5 path (needs ~17 MB)
        float* Vs = (float*)d_ws;
        float* sp = Vs + 65536;
        dim3 grid(8 * FNCH), blk(256);
        dim3 rg(256), rb(256);
        caps_route_fb<true ><<<grid, blk, 0, stream>>>(x, W, nullptr, sp);
        reduce_squash_fb<0><<<rg, rb, 0, stream>>>(sp, Vs, out);
        caps_route_fb<false><<<grid, blk, 0, stream>>>(x, W, Vs, sp);
        reduce_squash_fb<1><<<rg, rb, 0, stream>>>(sp, Vs, out);
        caps_route_fb<false><<<grid, blk, 0, stream>>>(x, W, Vs, sp);
        reduce_squash_fb<2><<<rg, rb, 0, stream>>>(sp, Vs, out);
    }
}

// Round 15
// 88.238 us; speedup vs baseline: 6.1534x; 1.0376x over previous
//
#include <hip/hip_runtime.h>
#include <math.h>

// B=64, N_in=1152, K_in=8, N_out=64, K_out=16, ITER=3
// MFMA path (round-11/14 structure) with W in bf16-HI ONLY:
// slots 0-7 = Whi*xhi, 8-15 = Whi*xlo, 16-31 = zeroed (A and B both zero).
// Halves Wp (37.7 -> 18.9 MB), halves LDS staging per step (64 KB dbuf total).
// x stays hi/lo split -> x at fp32 fidelity; W rounding adds ~3e-4 (budget ok).

#define CTI 18        // i per chunk
#define IPB 2         // i per buffer step
#define NSTEP 9       // CTI / IPB
#define CNCH 64       // 1152 / CTI

typedef __attribute__((ext_vector_type(8))) short short8v;
typedef __attribute__((ext_vector_type(8))) unsigned short ushort8v;
typedef __attribute__((ext_vector_type(4))) float f32x4;

typedef const __attribute__((address_space(1))) unsigned int gu32;
typedef __attribute__((address_space(3))) unsigned int lu32;

__device__ __forceinline__ unsigned short f2bf(float f) {   // RTNE
    unsigned u = __builtin_bit_cast(unsigned, f);
    u = u + 0x7FFFu + ((u >> 16) & 1u);
    return (unsigned short)(u >> 16);
}
__device__ __forceinline__ float bf2f(unsigned short h) {
    unsigned u = ((unsigned)h) << 16;
    return __builtin_bit_cast(float, u);
}
__device__ __forceinline__ float lo16f(unsigned u) {
    return __builtin_bit_cast(float, u << 16);
}
__device__ __forceinline__ float hi16f(unsigned u) {
    return __builtin_bit_cast(float, u & 0xFFFF0000u);
}

// W[o][i][k][j] f32 -> Wp[i][o][k][j] bf16 (HI only, 18.9 MB);
// x[b][i][j] f32 -> xp[i][p][b][j] bf16 hi/lo.
__global__ __launch_bounds__(256)
void xform(const float* __restrict__ W, const float* __restrict__ x,
           unsigned short* __restrict__ Wp, unsigned short* __restrict__ xpp) {
    const int bid = blockIdx.x;
    if (bid < 4608) {
        int tid = bid * 256 + threadIdx.x;          // 1152*64*16
        int k = tid & 15, o = (tid >> 4) & 63, i = tid >> 10;
        const float4* src = (const float4*)(W + (((size_t)o * 1152 + i) * 16 + k) * 8);
        float4 v0 = src[0], v1 = src[1];
        float vf[8] = {v0.x, v0.y, v0.z, v0.w, v1.x, v1.y, v1.z, v1.w};
        ushort8v hi;
        #pragma unroll
        for (int j = 0; j < 8; ++j) hi[j] = f2bf(vf[j]);
        *reinterpret_cast<ushort8v*>(Wp + (((size_t)i * 64 + o) * 16 + k) * 8) = hi;
    } else {
        int tid = (bid - 4608) * 256 + threadIdx.x; // 1152*64
        int b = tid & 63, i = tid >> 6;
        const float4* src = (const float4*)(x + ((size_t)b * 1152 + i) * 8);
        float4 v0 = src[0], v1 = src[1];
        float vf[8] = {v0.x, v0.y, v0.z, v0.w, v1.x, v1.y, v1.z, v1.w};
        ushort8v hi, lo;
        #pragma unroll
        for (int j = 0; j < 8; ++j) {
            unsigned short h = f2bf(vf[j]);
            hi[j] = h;
            lo[j] = f2bf(vf[j] - bf2f(h));
        }
        size_t base = ((size_t)i * 2) * 512 + (size_t)b * 8;
        *reinterpret_cast<ushort8v*>(xpp + base)       = hi;
        *reinterpret_cast<ushort8v*>(xpp + base + 512) = lo;
    }
}

// Routing pass. Grid 256 = btile(4) x chunk(64); btile-sharers of a chunk
// differ by 64 in blockIdx -> same XCD L2. Block: 1024 thr = 16 waves;
// wave wv owns o = wv*4..+4; lanes: col b = l&15 (= A-row k), group g = l>>4.
// Slot map (K=32): 0-7 Whi*xhi, 8-15 Whi*xlo, 16-31 zero (A=B=0 for g>=2).
// Wp staged 2 i-slices (32 KB) per step, double-buffered; ONE barrier/step.
template<int ROUTED>
__global__ __launch_bounds__(1024, 4)
void caps_mfma(const unsigned short* __restrict__ Wp,
               const unsigned short* __restrict__ xp,
               const float* __restrict__ Vfp,
               unsigned short* __restrict__ spart) {
    __shared__ unsigned short wlds[2][IPB * 8192];    // 2 x 32 KB (hi only)
    __shared__ float zbuf[2][IPB][256];               // [parity][sub-i][wave*16+b15]

    const int t = threadIdx.x;
    const int wv = t >> 6, l = t & 63;
    const int btile = blockIdx.x >> 6, chunk = blockIdx.x & 63;
    const int g = l >> 4, b15 = l & 15;
    const int o0 = wv * 4;
    const int i0 = chunk * CTI;
    const bool act = (g < 2);                 // lanes supplying nonzero slots

    // Vsum packed to bf16 pairs: 8 VGPRs
    uint2 vpk[4];
    if (ROUTED) {
        #pragma unroll
        for (int oo = 0; oo < 4; ++oo) {
            f32x4 Vf = *reinterpret_cast<const f32x4*>(
                Vfp + (((size_t)btile * 64 + o0 + oo) * 64 + l) * 4);
            vpk[oo].x = (unsigned)f2bf(Vf[0]) | ((unsigned)f2bf(Vf[1]) << 16);
            vpk[oo].y = (unsigned)f2bf(Vf[2]) | ((unsigned)f2bf(Vf[3]) << 16);
        }
    }

    f32x4 s[4];
    #pragma unroll
    for (int oo = 0; oo < 4; ++oo) s[oo] = (f32x4){0.f, 0.f, 0.f, 0.f};

    const short8v z8 = {0, 0, 0, 0, 0, 0, 0, 0};

    // DMA IPB consecutive i-slices (32 KB): 2 rounds x 16 waves x 64 lanes x 16 B
    #define STAGE2(buf, ibase)                                                    \
    {                                                                             \
        const ushort8v* srcb = reinterpret_cast<const ushort8v*>(                 \
            Wp + (size_t)(ibase) * 8192);                                         \
        _Pragma("unroll")                                                         \
        for (int r = 0; r < 2; ++r)                                               \
            __builtin_amdgcn_global_load_lds(                                     \
                (gu32*)(srcb + (r * 1024 + wv * 64 + l)),                         \
                (lu32*)&wlds[buf][(size_t)(r * 1024 + wv * 64) * 8], 16, 0, 0);   \
    }

    // B-frag for sub-i at global index i: plane = g (0=hi, 1=lo); zero for g>=2
    #define LOADB(i) (*reinterpret_cast<const short8v*>(                          \
        xp + (((size_t)(i) * 2 + g) * 64 + btile * 16 + b15) * 8))

    STAGE2(0, i0);
    short8v Bf0 = z8, Bf1 = z8;
    if (act) { Bf0 = LOADB(i0); Bf1 = LOADB(i0 + 1); }
    __syncthreads();   // prologue DMA complete

    // A-frag LDS offset (per sub-i base): row k = b15, j = 0..7 (16 B)
    const int aoffbase = b15 * 8;

    int cur = 0;
    for (int st = 0; st < NSTEP; ++st) {
        // prefetch next 2 slices; DMA drains at this step's single barrier
        short8v Bn0 = Bf0, Bn1 = Bf1;
        if (st + 1 < NSTEP) {
            STAGE2(cur ^ 1, i0 + (st + 1) * IPB);
            if (act) {
                Bn0 = LOADB(i0 + (st + 1) * IPB);
                Bn1 = LOADB(i0 + (st + 1) * IPB + 1);
            }
        }

        if (!ROUTED) {
            #pragma unroll
            for (int oo = 0; oo < 4; ++oo) {
                short8v Af0 = z8, Af1 = z8;
                if (act) {
                    const int ao = (o0 + oo) * 128 + aoffbase;
                    Af0 = *reinterpret_cast<const short8v*>(&wlds[cur][0] + ao);
                    Af1 = *reinterpret_cast<const short8v*>(&wlds[cur][8192] + ao);
                }
                s[oo] = __builtin_amdgcn_mfma_f32_16x16x32_bf16(Af0, Bf0, s[oo], 0, 0, 0);
                s[oo] = __builtin_amdgcn_mfma_f32_16x16x32_bf16(Af1, Bf1, s[oo], 0, 0, 0);
            }
            __syncthreads();   // DMA(next) complete + buffer-reuse safety
        } else {
            f32x4 u[IPB][4];
            float lg[IPB][4];
            float Zp0 = 0.f, Zp1 = 0.f;
            #pragma unroll
            for (int oo = 0; oo < 4; ++oo) {
                short8v Af0 = z8, Af1 = z8;
                if (act) {
                    const int ao = (o0 + oo) * 128 + aoffbase;
                    Af0 = *reinterpret_cast<const short8v*>(&wlds[cur][0] + ao);
                    Af1 = *reinterpret_cast<const short8v*>(&wlds[cur][8192] + ao);
                }
                f32x4 zz = {0.f, 0.f, 0.f, 0.f};
                u[0][oo] = __builtin_amdgcn_mfma_f32_16x16x32_bf16(Af0, Bf0, zz, 0, 0, 0);
                u[1][oo] = __builtin_amdgcn_mfma_f32_16x16x32_bf16(Af1, Bf1, zz, 0, 0, 0);

                float p0 = u[0][oo][0] * lo16f(vpk[oo].x);
                p0 = fmaf(u[0][oo][1], hi16f(vpk[oo].x), p0);
                p0 = fmaf(u[0][oo][2], lo16f(vpk[oo].y), p0);
                p0 = fmaf(u[0][oo][3], hi16f(vpk[oo].y), p0);
                float p1 = u[1][oo][0] * lo16f(vpk[oo].x);
                p1 = fmaf(u[1][oo][1], hi16f(vpk[oo].x), p1);
                p1 = fmaf(u[1][oo][2], lo16f(vpk[oo].y), p1);
                p1 = fmaf(u[1][oo][3], hi16f(vpk[oo].y), p1);
                p0 += __shfl_xor(p0, 16, 64);  p1 += __shfl_xor(p1, 16, 64);
                p0 += __shfl_xor(p0, 32, 64);  p1 += __shfl_xor(p1, 32, 64);
                // logits bounded (|logit| <= ~1.2): exp without max-subtraction
                float e0 = __expf(p0), e1 = __expf(p1);
                lg[0][oo] = e0; lg[1][oo] = e1;
                Zp0 += e0; Zp1 += e1;
            }
            if (l < 16) {
                zbuf[st & 1][0][wv * 16 + l] = Zp0;
                zbuf[st & 1][1][wv * 16 + l] = Zp1;
            }
            __syncthreads();                   // Z visible; DMA(next) drained
            float Z0 = zbuf[st & 1][0][b15];
            float Z1 = zbuf[st & 1][1][b15];
            #pragma unroll
            for (int w2 = 1; w2 < 16; ++w2) {
                Z0 += zbuf[st & 1][0][w2 * 16 + b15];
                Z1 += zbuf[st & 1][1][w2 * 16 + b15];
            }
            float rz0 = 1.0f / Z0, rz1 = 1.0f / Z1;
            #pragma unroll
            for (int oo = 0; oo < 4; ++oo) {
                float c0 = lg[0][oo] * rz0;
                float c1 = lg[1][oo] * rz1;
                s[oo][0] = fmaf(c0, u[0][oo][0], fmaf(c1, u[1][oo][0], s[oo][0]));
                s[oo][1] = fmaf(c0, u[0][oo][1], fmaf(c1, u[1][oo][1], s[oo][1]));
                s[oo][2] = fmaf(c0, u[0][oo][2], fmaf(c1, u[1][oo][2], s[oo][2]));
                s[oo][3] = fmaf(c0, u[0][oo][3], fmaf(c1, u[1][oo][3], s[oo][3]));
            }
        }
        Bf0 = Bn0; Bf1 = Bn1;
        cur ^= 1;
    }

    // bf16 partials: [chunk][btile][o][l][4k], 8 B/lane coalesced
    const float fin = ROUTED ? 1.0f : (1.0f / 64.0f);
    #pragma unroll
    for (int oo = 0; oo < 4; ++oo) {
        f32x4 vv = s[oo] * fin;
        uint2 pk;
        pk.x = (unsigned)f2bf(vv[0]) | ((unsigned)f2bf(vv[1]) << 16);
        pk.y = (unsigned)f2bf(vv[2]) | ((unsigned)f2bf(vv[3]) << 16);
        *reinterpret_cast<uint2*>(spart +
            ((((size_t)chunk * 4 + btile) * 64 + (o0 + oo)) * 64 + l) * 4) = pk;
    }
    #undef STAGE2
    #undef LOADB
}

// Sum CNCH bf16 chunk-partials, squash, update Vfp / write out.
// Grid 256 blocks (one (btile,o) pair) x 256 thr: l = t&63, cq = t>>6.
template<int MODE>
__global__ __launch_bounds__(256)
void reduce2(const unsigned short* __restrict__ spart, float* __restrict__ Vfp,
             float* __restrict__ out) {
    __shared__ f32x4 red[256];
    const int t = threadIdx.x;
    const int l = t & 63, cq = t >> 6;
    const int pair = blockIdx.x;               // btile*64 + o
    const int btile = pair >> 6, o = pair & 63;

    f32x4 acc = {0.f, 0.f, 0.f, 0.f};
    const unsigned short* base = spart + (((size_t)btile * 64 + o) * 64 + l) * 4;
    for (int c = cq * (CNCH/4); c < (cq + 1) * (CNCH/4); ++c) {
        uint2 w = *reinterpret_cast<const uint2*>(base + (size_t)c * 65536);
        acc[0] += lo16f(w.x); acc[1] += hi16f(w.x);
        acc[2] += lo16f(w.y); acc[3] += hi16f(w.y);
    }
    red[t] = acc;
    __syncthreads();
    if (cq == 0) {
        acc = red[l] + red[64 + l] + red[128 + l] + red[192 + l];
        float n2 = acc[0]*acc[0] + acc[1]*acc[1] + acc[2]*acc[2] + acc[3]*acc[3];
        n2 += __shfl_xor(n2, 16, 64);
        n2 += __shfl_xor(n2, 32, 64);
        const float scale = n2 / (1.0f + n2) / sqrtf(n2 + 1e-7f);
        f32x4 v = acc * scale;
        float* vp = Vfp + (((size_t)btile * 64 + o) * 64 + l) * 4;
        if (MODE == 0) {
            *reinterpret_cast<f32x4*>(vp) = v;
        } else if (MODE == 1) {
            f32x4 old = *reinterpret_cast<const f32x4*>(vp);
            *reinterpret_cast<f32x4*>(vp) = old + v;
        } else {
            const int b = btile * 16 + (l & 15), gq = l >> 4;
            *reinterpret_cast<f32x4*>(out + (((size_t)b * 64 + o) * 16 + gq * 4)) = v;
        }
    }
}

// ------------------------- round-5 fallback (small ws, proven) -------------------------
#define FTI 18
#define FNCH 64

__device__ __forceinline__ void load_lds16(const float4* gp, float4* lp) {
    __builtin_amdgcn_global_load_lds((gu32*)gp, (lu32*)lp, 16, 0, 0);
}
__device__ __forceinline__ float rfl(float v) {
    return __builtin_bit_cast(float, __builtin_amdgcn_readfirstlane(__builtin_bit_cast(int, v)));
}

template<bool UNIFORM>
__global__ __launch_bounds__(256, 2)
void caps_route_fb(const float* __restrict__ x, const float* __restrict__ W,
                   const float* __restrict__ Vsum, float* __restrict__ s_out) {
    __shared__ float4 wlds[2][2048];
    __shared__ float4 xlds[8 * FTI * 2];
    const int t = threadIdx.x;
    const int w = t >> 6, o = t & 63;
    const int chunk = blockIdx.x % FNCH, bblk = blockIdx.x / FNCH;
    const int i0 = chunk * FTI, bbase = bblk * 8 + w * 2;
    const float4* __restrict__ xg = (const float4*)x;
    const float4* __restrict__ Wg = (const float4*)W;
    for (int e = t; e < 8 * FTI * 2; e += 256) {
        int bb = e / (FTI * 2), r = e % (FTI * 2);
        xlds[e] = xg[((bblk * 8 + bb) * 1152 + i0 + (r >> 1)) * 2 + (r & 1)];
    }
    const float4* wsrc = Wg + (size_t)o * 36864 + (size_t)i0 * 32 + w * 8;
    #pragma unroll
    for (int r = 0; r < 8; ++r) load_lds16(wsrc + r, &wlds[0][(w * 8 + r) * 64]);
    float vsf[2][16];
    if (!UNIFORM) {
        const float4* vg = (const float4*)Vsum;
        #pragma unroll
        for (int ll = 0; ll < 2; ++ll)
            #pragma unroll
            for (int q = 0; q < 4; ++q) {
                float4 v = vg[((size_t)(bbase + ll) * 64 + o) * 4 + q];
                vsf[ll][q*4+0] = v.x; vsf[ll][q*4+1] = v.y;
                vsf[ll][q*4+2] = v.z; vsf[ll][q*4+3] = v.w;
            }
    }
    float sacc[2][16];
    #pragma unroll
    for (int ll = 0; ll < 2; ++ll)
        #pragma unroll
        for (int k = 0; k < 16; ++k) sacc[ll][k] = 0.0f;
    for (int ii = 0; ii < FTI; ++ii) {
        const int cur = ii & 1;
        __syncthreads();
        if (ii + 1 < FTI) {
            const float4* ws = wsrc + (size_t)(ii + 1) * 32;
            #pragma unroll
            for (int r = 0; r < 8; ++r) load_lds16(ws + r, &wlds[cur ^ 1][(w * 8 + r) * 64]);
        }
        float4 A0 = xlds[(w*2+0)*(FTI*2) + ii*2 + 0];
        float4 B0 = xlds[(w*2+0)*(FTI*2) + ii*2 + 1];
        float4 A1 = xlds[(w*2+1)*(FTI*2) + ii*2 + 0];
        float4 B1 = xlds[(w*2+1)*(FTI*2) + ii*2 + 1];
        float xa0x=rfl(A0.x),xa0y=rfl(A0.y),xa0z=rfl(A0.z),xa0w=rfl(A0.w);
        float xb0x=rfl(B0.x),xb0y=rfl(B0.y),xb0z=rfl(B0.z),xb0w=rfl(B0.w);
        float xa1x=rfl(A1.x),xa1y=rfl(A1.y),xa1z=rfl(A1.z),xa1w=rfl(A1.w);
        float xb1x=rfl(B1.x),xb1y=rfl(B1.y),xb1z=rfl(B1.z),xb1w=rfl(B1.w);
        const float4* wb = wlds[cur];
        float u[2][16];
        float logit0 = 0.0f, logit1 = 0.0f;
        #pragma unroll
        for (int k = 0; k < 16; ++k) {
            float4 w0 = wb[(2*k  )*64 + o];
            float4 w1 = wb[(2*k+1)*64 + o];
            float uk0 = w0.x*xa0x; uk0=fmaf(w0.y,xa0y,uk0); uk0=fmaf(w0.z,xa0z,uk0);
            uk0=fmaf(w0.w,xa0w,uk0); uk0=fmaf(w1.x,xb0x,uk0); uk0=fmaf(w1.y,xb0y,uk0);
            uk0=fmaf(w1.z,xb0z,uk0); uk0=fmaf(w1.w,xb0w,uk0);
            float uk1 = w0.x*xa1x; uk1=fmaf(w0.y,xa1y,uk1); uk1=fmaf(w0.z,xa1z,uk1);
            uk1=fmaf(w0.w,xa1w,uk1); uk1=fmaf(w1.x,xb1x,uk1); uk1=fmaf(w1.y,xb1y,uk1);
            uk1=fmaf(w1.z,xb1z,uk1); uk1=fmaf(w1.w,xb1w,uk1);
            u[0][k]=uk0; u[1][k]=uk1;
            if (!UNIFORM) { logit0=fmaf(vsf[0][k],uk0,logit0); logit1=fmaf(vsf[1][k],uk1,logit1); }
        }
        float c0, c1;
        if (UNIFORM) { c0 = c1 = 1.0f/64.0f; }
        else {
            float m0=logit0, m1=logit1;
            #pragma unroll
            for (int d=32; d>=1; d>>=1) { m0=fmaxf(m0,__shfl_xor(m0,d,64)); m1=fmaxf(m1,__shfl_xor(m1,d,64)); }
            float e0=__expf(logit0-m0), e1=__expf(logit1-m1);
            float s0=e0, s1=e1;
            #pragma unroll
            for (int d=32; d>=1; d>>=1) { s0+=__shfl_xor(s0,d,64); s1+=__shfl_xor(s1,d,64); }
            c0=e0/s0; c1=e1/s1;
        }
        #pragma unroll
        for (int k = 0; k < 16; ++k) {
            sacc[0][k]=fmaf(c0,u[0][k],sacc[0][k]);
            sacc[1][k]=fmaf(c1,u[1][k],sacc[1][k]);
        }
    }
    #pragma unroll
    for (int ll = 0; ll < 2; ++ll) {
        float4* sp = (float4*)s_out + (((size_t)chunk * 64 + (bbase + ll)) * 64 + o) * 4;
        sp[0]=make_float4(sacc[ll][0],sacc[ll][1],sacc[ll][2],sacc[ll][3]);
        sp[1]=make_float4(sacc[ll][4],sacc[ll][5],sacc[ll][6],sacc[ll][7]);
        sp[2]=make_float4(sacc[ll][8],sacc[ll][9],sacc[ll][10],sacc[ll][11]);
        sp[3]=make_float4(sacc[ll][12],sacc[ll][13],sacc[ll][14],sacc[ll][15]);
    }
}

template<int MODE>
__global__ __launch_bounds__(256)
void reduce_squash_fb(const float* __restrict__ sp, float* __restrict__ Vs, float* __restrict__ out) {
    const int t = threadIdx.x;
    const int p = t >> 4, q = t & 15;
    const int pair = blockIdx.x * 16 + p;
    const int b = pair >> 6, o = pair & 63;
    float acc[16];
    #pragma unroll
    for (int k = 0; k < 16; ++k) acc[k] = 0.0f;
    const float4* base = (const float4*)sp;
    for (int c = q * (FNCH/16); c < (q + 1) * (FNCH/16); ++c) {
        const float4* pptr = base + (((size_t)c * 64 + b) * 64 + o) * 4;
        float4 v0=pptr[0],v1=pptr[1],v2=pptr[2],v3=pptr[3];
        acc[0]+=v0.x;acc[1]+=v0.y;acc[2]+=v0.z;acc[3]+=v0.w;
        acc[4]+=v1.x;acc[5]+=v1.y;acc[6]+=v1.z;acc[7]+=v1.w;
        acc[8]+=v2.x;acc[9]+=v2.y;acc[10]+=v2.z;acc[11]+=v2.w;
        acc[12]+=v3.x;acc[13]+=v3.y;acc[14]+=v3.z;acc[15]+=v3.w;
    }
    #pragma unroll
    for (int d = 1; d < 16; d <<= 1)
        #pragma unroll
        for (int k = 0; k < 16; ++k) acc[k] += __shfl_xor(acc[k], d, 64);
    if (q == 0) {
        float n2 = 0.0f;
        #pragma unroll
        for (int k = 0; k < 16; ++k) n2 = fmaf(acc[k], acc[k], n2);
        const float scale = n2 / (1.0f + n2) / sqrtf(n2 + 1e-7f);
        if (MODE == 0) {
            float4* vf = (float4*)Vs + (size_t)pair * 4;
            #pragma unroll
            for (int r = 0; r < 4; ++r)
                vf[r] = make_float4(scale*acc[r*4+0],scale*acc[r*4+1],scale*acc[r*4+2],scale*acc[r*4+3]);
        } else if (MODE == 1) {
            float4* vf = (float4*)Vs + (size_t)pair * 4;
            #pragma unroll
            for (int r = 0; r < 4; ++r) {
                float4 v = vf[r];
                v.x=fmaf(scale,acc[r*4+0],v.x); v.y=fmaf(scale,acc[r*4+1],v.y);
                v.z=fmaf(scale,acc[r*4+2],v.z); v.w=fmaf(scale,acc[r*4+3],v.w);
                vf[r] = v;
            }
        } else {
            float4* of = (float4*)out + (size_t)pair * 4;
            #pragma unroll
            for (int r = 0; r < 4; ++r)
                of[r] = make_float4(scale*acc[r*4+0],scale*acc[r*4+1],scale*acc[r*4+2],scale*acc[r*4+3]);
        }
    }
}
// -----------------------------------------------------------------------------

extern "C" void kernel_launch(void* const* d_in, const int* in_sizes, int n_in,
                              void* d_out, int out_size, void* d_ws, size_t ws_size,
                              hipStream_t stream) {
    const float* x = (const float*)d_in[0];   // [64,1152,8]
    const float* W = (const float*)d_in[1];   // [64,1152,16,8]
    float* out = (float*)d_out;               // [64,64,16]

    float* Vfp = (float*)d_ws;                                       // 65536 f32
    unsigned short* spart = (unsigned short*)(Vfp + 65536);          // CNCH*65536 bf16
    unsigned short* Wp = spart + (size_t)CNCH * 65536;               // hi-only: 9.4M ushorts
    unsigned short* xpp = Wp + (size_t)1152 * 64 * 128;
    const size_t need_full = (size_t)65536 * 4
        + ((size_t)CNCH * 65536 + (size_t)1152 * 64 * 128 + (size_t)1152 * 2 * 512) * 2;

    if (ws_size >= need_full) {
        xform<<<4608 + 288, 256, 0, stream>>>(W, x, Wp, xpp);
        caps_mfma<0><<<256, 1024, 0, stream>>>(Wp, xpp, Vfp, spart);
        reduce2<0><<<256, 256, 0, stream>>>(spart, Vfp, out);
        caps_mfma<1><<<256, 1024, 0, stream>>>(Wp, xpp, Vfp, spart);
        reduce2<1><<<256, 256, 0, stream>>>(spart, Vfp, out);
        caps_mfma<1><<<256, 1024, 0, stream>>>(Wp, xpp, Vfp, spart);
        reduce2<2><<<256, 256, 0, stream>>>(spart, Vfp, out);
    } else {
        // proven round-5 path (needs ~17 MB)
        float* Vs = (float*)d_ws;
        float* sp = Vs + 65536;
        dim3 grid(8 * FNCH), blk(256);
        dim3 rg(256), rb(256);
        caps_route_fb<true ><<<grid, blk, 0, stream>>>(x, W, nullptr, sp);
        reduce_squash_fb<0><<<rg, rb, 0, stream>>>(sp, Vs, out);
        caps_route_fb<false><<<grid, blk, 0, stream>>>(x, W, Vs, sp);
        reduce_squash_fb<1><<<rg, rb, 0, stream>>>(sp, Vs, out);
        caps_route_fb<false><<<grid, blk, 0, stream>>>(x, W, Vs, sp);
        reduce_squash_fb<2><<<rg, rb, 0, stream>>>(sp, Vs, out);
    }
}